// Round 6
// baseline (227.448 us; speedup 1.0000x reference)
//
#include <hip/hip_runtime.h>

#define BATCH 8
#define CIN   64
#define COUT  64
#define Hdim  128
#define Wdim  128
#define HW    (Hdim * Wdim)

typedef unsigned short ushort_t;
typedef unsigned short ushort8 __attribute__((ext_vector_type(8)));
typedef short short8 __attribute__((ext_vector_type(8)));
typedef unsigned int u32x4 __attribute__((ext_vector_type(4)));
typedef float f32x2 __attribute__((ext_vector_type(2)));
typedef float f32x4 __attribute__((ext_vector_type(4)));

__device__ __forceinline__ ushort_t f2b(float f) {
    unsigned int u = __float_as_uint(f);
    return (ushort_t)((u + 0x8000u) >> 16);
}
__device__ __forceinline__ f32x2 unpk(unsigned int u) {
    f32x2 v;
    v.x = __uint_as_float(u << 16);
    v.y = __uint_as_float(u & 0xffff0000u);
    return v;
}
__device__ __forceinline__ unsigned int pack2(f32x2 v) {
    unsigned int lo = (__float_as_uint(v.x) + 0x8000u) >> 16;
    unsigned int hi = (__float_as_uint(v.y) + 0x8000u) & 0xffff0000u;
    return lo | hi;
}

// blend 4 corners (8 channels each, packed u32x4) -> bf16 A-fragment
__device__ __forceinline__ short8 blend8(u32x4 c00, u32x4 c01, u32x4 c10, u32x4 c11,
                                         float w00, float w01, float w10, float w11) {
    u32x4 t;
#pragma unroll
    for (int i = 0; i < 4; ++i) {
        f32x2 v = unpk(c00[i]) * w00;
        v += unpk(c01[i]) * w01;
        v += unpk(c10[i]) * w10;
        v += unpk(c11[i]) * w11;
        t[i] = pack2(v);
    }
    return *(short8*)&t;
}

// ---------------- prep: x (B,C,H,W) f32 -> xt (B,H,W,C) bf16
//                   w (O,C,3,3) f32 -> wt2[k][f][lane][8] exact B-frag order
__global__ __launch_bounds__(256) void dcnv2_prep(
    const float* __restrict__ x, const float* __restrict__ w,
    ushort_t* __restrict__ xt, ushort_t* __restrict__ wt2)
{
    int bid = blockIdx.x;
    if (bid < 4096) {
        int g = bid * 256 + threadIdx.x;          // B*HW*8 = 1,048,576
        int pixel = g >> 3;
        int c0 = (g & 7) << 3;
        int b = pixel >> 14, hw = pixel & (HW - 1);
        const float* xp = x + (size_t)(b * CIN + c0) * HW + hw;
        ushort8 o;
#pragma unroll
        for (int i = 0; i < 8; ++i) o[i] = f2b(xp[(size_t)i * HW]);
        *(ushort8*)(xt + (size_t)pixel * 64 + c0) = o;
    } else {
        int t2 = (bid - 4096) * 256 + threadIdx.x; // 0..4607
        if (t2 < 9 * 8 * 64) {
            int k = t2 >> 9;           // tap
            int f = (t2 >> 6) & 7;     // frag id: f = s*4 + n
            int L = t2 & 63;           // lane
            int n = f & 3;
            int s = f >> 2;
            int o = n * 16 + (L & 15);
            int chb = s * 32 + ((L >> 4) << 3);
            const float* wp = w + (size_t)o * 576 + (size_t)chb * 9 + k;
            ushort_t* dst = wt2 + k * 4096 + f * 512 + L * 8;
#pragma unroll
            for (int j = 0; j < 8; ++j) dst[j] = f2b(wp[(size_t)j * 9]);
        }
    }
}

// ---------------- main: wave-autonomous im2col-in-registers + MFMA.
// 1024 thr (16 waves), one wave = 16 px x 64 outs. Lane L gathers pixel
// (L&15), chans (L>>4)*8 (+32) -> blended regs ARE the A-fragment.
// ALL 9 taps' B-fragments staged once in 72KB LDS (one barrier, then none).
// 2 blocks/CU (LDS-capped), VGPR<=64 -> 8 waves/SIMD.
__global__ __launch_bounds__(1024, 8) void dcnv2_mfma(
    const ushort_t* __restrict__ xt,   // (B,H,W,C) bf16
    const ushort_t* __restrict__ wt2,  // (9,8,64,8) bf16 frag-ordered
    const float* __restrict__ off,     // (B,18,H,W)
    const float* __restrict__ msk,     // (B,9,H,W)
    const float* __restrict__ bias,    // (O)
    float* __restrict__ out)           // (B,O,H,W)
{
    __shared__ ushort_t wlds[9 * 4096];   // 73,728 B: all taps, frag-ordered

    int tid = threadIdx.x;
    int bid = blockIdx.x;
    int swz = (bid & 7) * 64 + (bid >> 3);    // XCD swizzle (512 % 8 == 0)

    // ---- stage full weight table to LDS (linear, coalesced), one barrier
    for (int i = tid; i < 4608; i += 1024)
        *(u32x4*)(wlds + (size_t)i * 8) = *(const u32x4*)(wt2 + (size_t)i * 8);
    __syncthreads();

    int wv = tid >> 6;
    int lane = tid & 63;
    int gwid = swz * 16 + wv;                 // 0..8191
    int pbase = gwid << 4;                    // 16 px per wave
    int bb = pbase >> 14;
    int hwb = pbase & (HW - 1);
    int r = lane & 15, hi4 = lane >> 4;
    int hw = hwb + r;
    int y = hw >> 7, xq = hw & (Wdim - 1);

    const float* offb = off + (size_t)bb * 18 * HW + hw;
    const float* mb   = msk + (size_t)bb * 9 * HW + hw;
    const ushort_t* xtb = xt + ((size_t)bb << 20);
    const ushort_t* wlp = wlds + lane * 8;    // + k*4096 + f*512
    int ch0 = hi4 << 3;                       // s=0 chunk; s=1 at +32

    f32x4 acc[4];
#pragma unroll
    for (int n = 0; n < 4; ++n) acc[n] = (f32x4){0.f, 0.f, 0.f, 0.f};

    float oy_c = offb[0];
    float ox_c = offb[HW];
    float mk_c = mb[0];

#pragma unroll 1
    for (int k = 0; k < 9; ++k) {
        float oy_n = 0.f, ox_n = 0.f, mk_n = 0.f;
        if (k < 8) {
            oy_n = offb[(size_t)(2 * k + 2) * HW];
            ox_n = offb[(size_t)(2 * k + 3) * HW];
            mk_n = mb[(size_t)(k + 1) * HW];
        }

        int ky = k / 3;
        int kx = k - ky * 3;
        float py = (float)(y - 1 + ky) + oy_c;
        float px = (float)(xq - 1 + kx) + ox_c;
        float fy = floorf(py), fx = floorf(px);
        float ly = py - fy, lx = px - fx;
        float hy = 1.f - ly, hx = 1.f - lx;
        int y0 = (int)fy, x0 = (int)fx;
        int y1 = y0 + 1, x1 = x0 + 1;
        float vy0 = (y0 >= 0 && y0 < Hdim) ? mk_c : 0.f;
        float vy1 = (y1 >= 0 && y1 < Hdim) ? mk_c : 0.f;
        float vx0 = (x0 >= 0 && x0 < Wdim) ? 1.f : 0.f;
        float vx1 = (x1 >= 0 && x1 < Wdim) ? 1.f : 0.f;
        float w00 = hy * hx * vy0 * vx0, w01 = hy * lx * vy0 * vx1;
        float w10 = ly * hx * vy1 * vx0, w11 = ly * lx * vy1 * vx1;
        int cy0 = min(max(y0, 0), Hdim - 1), cy1 = min(max(y1, 0), Hdim - 1);
        int cx0 = min(max(x0, 0), Wdim - 1), cx1 = min(max(x1, 0), Wdim - 1);

        const ushort_t* p00 = xtb + (((cy0 << 7) + cx0) << 6) + ch0;
        const ushort_t* p01 = xtb + (((cy0 << 7) + cx1) << 6) + ch0;
        const ushort_t* p10 = xtb + (((cy1 << 7) + cx0) << 6) + ch0;
        const ushort_t* p11 = xtb + (((cy1 << 7) + cx1) << 6) + ch0;

        // 8 x 16B corner loads (s=0 chunk, s=1 chunk at +32 ch)
        u32x4 a00 = *(const u32x4*)p00, h00 = *(const u32x4*)(p00 + 32);
        u32x4 a01 = *(const u32x4*)p01, h01 = *(const u32x4*)(p01 + 32);
        u32x4 a10 = *(const u32x4*)p10, h10 = *(const u32x4*)(p10 + 32);
        u32x4 a11 = *(const u32x4*)p11, h11 = *(const u32x4*)(p11 + 32);

        // 8 B-fragment ds_read_b128 (lane*16B -> max-BW, conflict-free)
        const ushort_t* wk = wlp + k * 4096;
        short8 b0 = *(const short8*)(wk);
        short8 b1 = *(const short8*)(wk + 512);
        short8 b2 = *(const short8*)(wk + 1024);
        short8 b3 = *(const short8*)(wk + 1536);
        short8 b4 = *(const short8*)(wk + 2048);
        short8 b5 = *(const short8*)(wk + 2560);
        short8 b6 = *(const short8*)(wk + 3072);
        short8 b7 = *(const short8*)(wk + 3584);

        short8 af0 = blend8(a00, a01, a10, a11, w00, w01, w10, w11);
        short8 af1 = blend8(h00, h01, h10, h11, w00, w01, w10, w11);

        acc[0] = __builtin_amdgcn_mfma_f32_16x16x32_bf16(af0, b0, acc[0], 0, 0, 0);
        acc[1] = __builtin_amdgcn_mfma_f32_16x16x32_bf16(af0, b1, acc[1], 0, 0, 0);
        acc[2] = __builtin_amdgcn_mfma_f32_16x16x32_bf16(af0, b2, acc[2], 0, 0, 0);
        acc[3] = __builtin_amdgcn_mfma_f32_16x16x32_bf16(af0, b3, acc[3], 0, 0, 0);
        acc[0] = __builtin_amdgcn_mfma_f32_16x16x32_bf16(af1, b4, acc[0], 0, 0, 0);
        acc[1] = __builtin_amdgcn_mfma_f32_16x16x32_bf16(af1, b5, acc[1], 0, 0, 0);
        acc[2] = __builtin_amdgcn_mfma_f32_16x16x32_bf16(af1, b6, acc[2], 0, 0, 0);
        acc[3] = __builtin_amdgcn_mfma_f32_16x16x32_bf16(af1, b7, acc[3], 0, 0, 0);

        oy_c = oy_n; ox_c = ox_n; mk_c = mk_n;
    }

    // ---- epilogue: D col = out (lane&15), D row = pixel hi4*4+j
    float* ob = out + ((size_t)bb << 6) * HW;
#pragma unroll
    for (int n = 0; n < 4; ++n) {
        int o = n * 16 + (lane & 15);
        float bv = bias[o];
#pragma unroll
        for (int j = 0; j < 4; ++j) {
            int ploc = (hi4 << 2) + j;
            ob[((size_t)o << 14) + hwb + ploc] = acc[n][j] + bv;
        }
    }
}

// ---------------- fallback (direct fp32 kernel) if ws too small
__global__ __launch_bounds__(256) void dcnv2_direct(
    const float* __restrict__ x, const float* __restrict__ off,
    const float* __restrict__ msk, const float* __restrict__ wgt,
    const float* __restrict__ bias, float* __restrict__ out)
{
    int pg = blockIdx.x * 256 + threadIdx.x;
    int b = pg >> 14;
    int hw = pg & (HW - 1);
    int y = hw >> 7;
    int xq = hw & (Wdim - 1);
    float acc[COUT];
#pragma unroll
    for (int o = 0; o < COUT; ++o) acc[o] = 0.0f;
    const float* xb = x + b * CIN * HW;
    const float* offb = off + b * 18 * HW + hw;
    const float* mb = msk + b * 9 * HW + hw;
    for (int k = 0; k < 9; ++k) {
        int ky = k / 3, kx = k % 3;
        float py = (float)(y - 1 + ky) + offb[(2 * k) * HW];
        float px = (float)(xq - 1 + kx) + offb[(2 * k + 1) * HW];
        float m = mb[k * HW];
        float fy = floorf(py), fx = floorf(px);
        float ly = py - fy, lx = px - fx;
        float hy = 1.0f - ly, hx = 1.0f - lx;
        int y0 = (int)fy, x0 = (int)fx;
        int y1 = y0 + 1, x1 = x0 + 1;
        float vy0 = (y0 >= 0 && y0 < Hdim) ? 1.f : 0.f;
        float vy1 = (y1 >= 0 && y1 < Hdim) ? 1.f : 0.f;
        float vx0 = (x0 >= 0 && x0 < Wdim) ? 1.f : 0.f;
        float vx1 = (x1 >= 0 && x1 < Wdim) ? 1.f : 0.f;
        float w00 = hy * hx * vy0 * vx0 * m, w01 = hy * lx * vy0 * vx1 * m;
        float w10 = ly * hx * vy1 * vx0 * m, w11 = ly * lx * vy1 * vx1 * m;
        int cy0 = min(max(y0, 0), Hdim - 1), cy1 = min(max(y1, 0), Hdim - 1);
        int cx0 = min(max(x0, 0), Wdim - 1), cx1 = min(max(x1, 0), Wdim - 1);
        int i00 = cy0 * Wdim + cx0, i01 = cy0 * Wdim + cx1;
        int i10 = cy1 * Wdim + cx0, i11 = cy1 * Wdim + cx1;
        const float* wk = wgt + k;
        const float* xc = xb;
        for (int c = 0; c < CIN; ++c) {
            float val = w00 * xc[i00] + w01 * xc[i01] + w10 * xc[i10] + w11 * xc[i11];
            const float* wc = wk + c * 9;
#pragma unroll
            for (int o = 0; o < COUT; ++o)
                acc[o] = fmaf(wc[o * (CIN * 9)], val, acc[o]);
            xc += HW;
        }
    }
    float* op = out + b * COUT * HW + hw;
#pragma unroll
    for (int o = 0; o < COUT; ++o) op[o * HW] = acc[o] + bias[o];
}

extern "C" void kernel_launch(void* const* d_in, const int* in_sizes, int n_in,
                              void* d_out, int out_size, void* d_ws, size_t ws_size,
                              hipStream_t stream) {
    const float* x    = (const float*)d_in[0];
    const float* off  = (const float*)d_in[1];
    const float* msk  = (const float*)d_in[2];
    const float* wgt  = (const float*)d_in[3];
    const float* bias = (const float*)d_in[4];
    float* out = (float*)d_out;

    const size_t xt_elems = (size_t)BATCH * HW * 64;   // 8,388,608 bf16
    const size_t wt_elems = 9 * 8 * 64 * 8;            // 36,864 bf16
    const size_t need = (xt_elems + wt_elems) * sizeof(ushort_t);

    if (ws_size < need) {
        dcnv2_direct<<<(BATCH * HW) / 256, 256, 0, stream>>>(x, off, msk, wgt, bias, out);
        return;
    }

    ushort_t* xt  = (ushort_t*)d_ws;
    ushort_t* wt2 = xt + xt_elems;

    dcnv2_prep<<<4096 + 18, 256, 0, stream>>>(x, wgt, xt, wt2);
    dcnv2_mfma<<<512, 1024, 0, stream>>>(xt, wt2, off, msk, bias, out);
}

// Round 7
// 86.352 us; speedup vs baseline: 2.6339x; 2.6339x over previous
//
#include <hip/hip_runtime.h>

#define BATCH 8
#define CIN   64
#define COUT  64
#define Hdim  128
#define Wdim  128
#define HW    (Hdim * Wdim)

typedef unsigned short ushort_t;
typedef unsigned short ushort8 __attribute__((ext_vector_type(8)));
typedef short short8 __attribute__((ext_vector_type(8)));
typedef unsigned int u32x4 __attribute__((ext_vector_type(4)));
typedef float f32x2 __attribute__((ext_vector_type(2)));
typedef float f32x4 __attribute__((ext_vector_type(4)));

__device__ __forceinline__ ushort_t f2b(float f) {
    unsigned int u = __float_as_uint(f);
    return (ushort_t)((u + 0x8000u) >> 16);
}
__device__ __forceinline__ f32x2 unpk(unsigned int u) {
    f32x2 v;
    v.x = __uint_as_float(u << 16);
    v.y = __uint_as_float(u & 0xffff0000u);
    return v;
}
__device__ __forceinline__ unsigned int pack2(f32x2 v) {
    unsigned int lo = (__float_as_uint(v.x) + 0x8000u) >> 16;
    unsigned int hi = (__float_as_uint(v.y) + 0x8000u) & 0xffff0000u;
    return lo | hi;
}

// blend 4 corners (8 channels each, packed u32x4) -> bf16 A-fragment
__device__ __forceinline__ short8 blend8(u32x4 c00, u32x4 c01, u32x4 c10, u32x4 c11,
                                         float w00, float w01, float w10, float w11) {
    u32x4 t;
#pragma unroll
    for (int i = 0; i < 4; ++i) {
        f32x2 v = unpk(c00[i]) * w00;
        v += unpk(c01[i]) * w01;
        v += unpk(c10[i]) * w10;
        v += unpk(c11[i]) * w11;
        t[i] = pack2(v);
    }
    return *(short8*)&t;
}

// ---------------- prep: x (B,C,H,W) f32 -> xt (B,H,W,C) bf16
//                   w (O,C,3,3) f32 -> wt2[k][f][lane][8] exact B-frag order
__global__ __launch_bounds__(256) void dcnv2_prep(
    const float* __restrict__ x, const float* __restrict__ w,
    ushort_t* __restrict__ xt, ushort_t* __restrict__ wt2)
{
    int bid = blockIdx.x;
    if (bid < 4096) {
        int g = bid * 256 + threadIdx.x;          // B*HW*8 = 1,048,576
        int pixel = g >> 3;
        int c0 = (g & 7) << 3;
        int b = pixel >> 14, hw = pixel & (HW - 1);
        const float* xp = x + (size_t)(b * CIN + c0) * HW + hw;
        ushort8 o;
#pragma unroll
        for (int i = 0; i < 8; ++i) o[i] = f2b(xp[(size_t)i * HW]);
        *(ushort8*)(xt + (size_t)pixel * 64 + c0) = o;
    } else {
        int t2 = (bid - 4096) * 256 + threadIdx.x; // 0..4607
        if (t2 < 9 * 8 * 64) {
            int k = t2 >> 9;           // tap
            int f = (t2 >> 6) & 7;     // frag id: f = s*4 + n
            int L = t2 & 63;           // lane
            int n = f & 3;
            int s = f >> 2;
            int o = n * 16 + (L & 15);
            int chb = s * 32 + ((L >> 4) << 3);
            const float* wp = w + (size_t)o * 576 + (size_t)chb * 9 + k;
            ushort_t* dst = wt2 + k * 4096 + f * 512 + L * 8;
#pragma unroll
            for (int j = 0; j < 8; ++j) dst[j] = f2b(wp[(size_t)j * 9]);
        }
    }
}

// ---------------- main: wave-autonomous im2col-in-registers + MFMA.
// 512 thr (8 waves), one wave = 16 px x 64 outs. Lane L gathers pixel (L&15),
// chans (L>>4)*8 (+32) -> blended regs ARE the A-fragment. All 9 taps'
// B-fragments staged once in 72KB LDS (one barrier, then barrier-free).
// LDS caps 2 blocks/CU = 16 waves/CU; natural VGPR (no min-waves coercion).
__global__ __launch_bounds__(512) void dcnv2_mfma(
    const ushort_t* __restrict__ xt,   // (B,H,W,C) bf16
    const ushort_t* __restrict__ wt2,  // (9,8,64,8) bf16 frag-ordered
    const float* __restrict__ off,     // (B,18,H,W)
    const float* __restrict__ msk,     // (B,9,H,W)
    const float* __restrict__ bias,    // (O)
    float* __restrict__ out)           // (B,O,H,W)
{
    __shared__ ushort_t wlds[9 * 4096];   // 73,728 B: all taps, frag-ordered

    int tid = threadIdx.x;
    int bid = blockIdx.x;
    int swz = (bid & 7) * 128 + (bid >> 3);   // XCD swizzle (1024 % 8 == 0)

    // ---- stage full weight table to LDS (coalesced), one barrier total
#pragma unroll
    for (int it = 0; it < 9; ++it) {
        int i = it * 512 + tid;
        *(u32x4*)(wlds + (size_t)i * 8) = *(const u32x4*)(wt2 + (size_t)i * 8);
    }
    __syncthreads();

    int wv = tid >> 6;
    int lane = tid & 63;
    int gwid = swz * 8 + wv;                  // 0..8191
    int pbase = gwid << 4;                    // 16 px per wave
    int bb = pbase >> 14;
    int hwb = pbase & (HW - 1);
    int r = lane & 15, hi4 = lane >> 4;
    int hw = hwb + r;
    int y = hw >> 7, xq = hw & (Wdim - 1);

    const float* offb = off + (size_t)bb * 18 * HW + hw;
    const float* mb   = msk + (size_t)bb * 9 * HW + hw;
    const ushort_t* xtb = xt + ((size_t)bb << 20);
    const ushort_t* wlp = wlds + lane * 8;    // + k*4096 + f*512
    int ch0 = hi4 << 3;                       // s=0 chunk; s=1 at +32

    f32x4 acc[4];
#pragma unroll
    for (int n = 0; n < 4; ++n) acc[n] = (f32x4){0.f, 0.f, 0.f, 0.f};

    float oy_c = offb[0];
    float ox_c = offb[HW];
    float mk_c = mb[0];

#pragma unroll 1
    for (int k = 0; k < 9; ++k) {
        float oy_n = 0.f, ox_n = 0.f, mk_n = 0.f;
        if (k < 8) {
            oy_n = offb[(size_t)(2 * k + 2) * HW];
            ox_n = offb[(size_t)(2 * k + 3) * HW];
            mk_n = mb[(size_t)(k + 1) * HW];
        }

        int ky = k / 3;
        int kx = k - ky * 3;
        float py = (float)(y - 1 + ky) + oy_c;
        float px = (float)(xq - 1 + kx) + ox_c;
        float fy = floorf(py), fx = floorf(px);
        float ly = py - fy, lx = px - fx;
        float hy = 1.f - ly, hx = 1.f - lx;
        int y0 = (int)fy, x0 = (int)fx;
        int y1 = y0 + 1, x1 = x0 + 1;
        float vy0 = (y0 >= 0 && y0 < Hdim) ? mk_c : 0.f;
        float vy1 = (y1 >= 0 && y1 < Hdim) ? mk_c : 0.f;
        float vx0 = (x0 >= 0 && x0 < Wdim) ? 1.f : 0.f;
        float vx1 = (x1 >= 0 && x1 < Wdim) ? 1.f : 0.f;
        float w00 = hy * hx * vy0 * vx0, w01 = hy * lx * vy0 * vx1;
        float w10 = ly * hx * vy1 * vx0, w11 = ly * lx * vy1 * vx1;
        int cy0 = min(max(y0, 0), Hdim - 1), cy1 = min(max(y1, 0), Hdim - 1);
        int cx0 = min(max(x0, 0), Wdim - 1), cx1 = min(max(x1, 0), Wdim - 1);

        const ushort_t* p00 = xtb + (((cy0 << 7) + cx0) << 6) + ch0;
        const ushort_t* p01 = xtb + (((cy0 << 7) + cx1) << 6) + ch0;
        const ushort_t* p10 = xtb + (((cy1 << 7) + cx0) << 6) + ch0;
        const ushort_t* p11 = xtb + (((cy1 << 7) + cx1) << 6) + ch0;

        // 8 x 16B corner loads (s=0 chunk, s=1 chunk at +32 ch)
        u32x4 a00 = *(const u32x4*)p00, h00 = *(const u32x4*)(p00 + 32);
        u32x4 a01 = *(const u32x4*)p01, h01 = *(const u32x4*)(p01 + 32);
        u32x4 a10 = *(const u32x4*)p10, h10 = *(const u32x4*)(p10 + 32);
        u32x4 a11 = *(const u32x4*)p11, h11 = *(const u32x4*)(p11 + 32);

        // 8 B-fragment ds_read_b128 (lane*16B, conflict-free)
        const ushort_t* wk = wlp + k * 4096;
        short8 b0 = *(const short8*)(wk);
        short8 b1 = *(const short8*)(wk + 512);
        short8 b2 = *(const short8*)(wk + 1024);
        short8 b3 = *(const short8*)(wk + 1536);
        short8 b4 = *(const short8*)(wk + 2048);
        short8 b5 = *(const short8*)(wk + 2560);
        short8 b6 = *(const short8*)(wk + 3072);
        short8 b7 = *(const short8*)(wk + 3584);

        short8 af0 = blend8(a00, a01, a10, a11, w00, w01, w10, w11);
        short8 af1 = blend8(h00, h01, h10, h11, w00, w01, w10, w11);

        __builtin_amdgcn_s_setprio(1);
        acc[0] = __builtin_amdgcn_mfma_f32_16x16x32_bf16(af0, b0, acc[0], 0, 0, 0);
        acc[1] = __builtin_amdgcn_mfma_f32_16x16x32_bf16(af0, b1, acc[1], 0, 0, 0);
        acc[2] = __builtin_amdgcn_mfma_f32_16x16x32_bf16(af0, b2, acc[2], 0, 0, 0);
        acc[3] = __builtin_amdgcn_mfma_f32_16x16x32_bf16(af0, b3, acc[3], 0, 0, 0);
        acc[0] = __builtin_amdgcn_mfma_f32_16x16x32_bf16(af1, b4, acc[0], 0, 0, 0);
        acc[1] = __builtin_amdgcn_mfma_f32_16x16x32_bf16(af1, b5, acc[1], 0, 0, 0);
        acc[2] = __builtin_amdgcn_mfma_f32_16x16x32_bf16(af1, b6, acc[2], 0, 0, 0);
        acc[3] = __builtin_amdgcn_mfma_f32_16x16x32_bf16(af1, b7, acc[3], 0, 0, 0);
        __builtin_amdgcn_s_setprio(0);

        oy_c = oy_n; ox_c = ox_n; mk_c = mk_n;
    }

    // ---- epilogue: D col = out (lane&15), D row = pixel hi4*4+j
    float* ob = out + ((size_t)bb << 6) * HW;
#pragma unroll
    for (int n = 0; n < 4; ++n) {
        int o = n * 16 + (lane & 15);
        float bv = bias[o];
#pragma unroll
        for (int j = 0; j < 4; ++j) {
            int ploc = (hi4 << 2) + j;
            ob[((size_t)o << 14) + hwb + ploc] = acc[n][j] + bv;
        }
    }
}

// ---------------- fallback (direct fp32 kernel) if ws too small
__global__ __launch_bounds__(256) void dcnv2_direct(
    const float* __restrict__ x, const float* __restrict__ off,
    const float* __restrict__ msk, const float* __restrict__ wgt,
    const float* __restrict__ bias, float* __restrict__ out)
{
    int pg = blockIdx.x * 256 + threadIdx.x;
    int b = pg >> 14;
    int hw = pg & (HW - 1);
    int y = hw >> 7;
    int xq = hw & (Wdim - 1);
    float acc[COUT];
#pragma unroll
    for (int o = 0; o < COUT; ++o) acc[o] = 0.0f;
    const float* xb = x + b * CIN * HW;
    const float* offb = off + b * 18 * HW + hw;
    const float* mb = msk + b * 9 * HW + hw;
    for (int k = 0; k < 9; ++k) {
        int ky = k / 3, kx = k % 3;
        float py = (float)(y - 1 + ky) + offb[(2 * k) * HW];
        float px = (float)(xq - 1 + kx) + offb[(2 * k + 1) * HW];
        float m = mb[k * HW];
        float fy = floorf(py), fx = floorf(px);
        float ly = py - fy, lx = px - fx;
        float hy = 1.0f - ly, hx = 1.0f - lx;
        int y0 = (int)fy, x0 = (int)fx;
        int y1 = y0 + 1, x1 = x0 + 1;
        float vy0 = (y0 >= 0 && y0 < Hdim) ? 1.f : 0.f;
        float vy1 = (y1 >= 0 && y1 < Hdim) ? 1.f : 0.f;
        float vx0 = (x0 >= 0 && x0 < Wdim) ? 1.f : 0.f;
        float vx1 = (x1 >= 0 && x1 < Wdim) ? 1.f : 0.f;
        float w00 = hy * hx * vy0 * vx0 * m, w01 = hy * lx * vy0 * vx1 * m;
        float w10 = ly * hx * vy1 * vx0 * m, w11 = ly * lx * vy1 * vx1 * m;
        int cy0 = min(max(y0, 0), Hdim - 1), cy1 = min(max(y1, 0), Hdim - 1);
        int cx0 = min(max(x0, 0), Wdim - 1), cx1 = min(max(x1, 0), Wdim - 1);
        int i00 = cy0 * Wdim + cx0, i01 = cy0 * Wdim + cx1;
        int i10 = cy1 * Wdim + cx0, i11 = cy1 * Wdim + cx1;
        const float* wk = wgt + k;
        const float* xc = xb;
        for (int c = 0; c < CIN; ++c) {
            float val = w00 * xc[i00] + w01 * xc[i01] + w10 * xc[i10] + w11 * xc[i11];
            const float* wc = wk + c * 9;
#pragma unroll
            for (int o = 0; o < COUT; ++o)
                acc[o] = fmaf(wc[o * (CIN * 9)], val, acc[o]);
            xc += HW;
        }
    }
    float* op = out + b * COUT * HW + hw;
#pragma unroll
    for (int o = 0; o < COUT; ++o) op[o * HW] = acc[o] + bias[o];
}

extern "C" void kernel_launch(void* const* d_in, const int* in_sizes, int n_in,
                              void* d_out, int out_size, void* d_ws, size_t ws_size,
                              hipStream_t stream) {
    const float* x    = (const float*)d_in[0];
    const float* off  = (const float*)d_in[1];
    const float* msk  = (const float*)d_in[2];
    const float* wgt  = (const float*)d_in[3];
    const float* bias = (const float*)d_in[4];
    float* out = (float*)d_out;

    const size_t xt_elems = (size_t)BATCH * HW * 64;   // 8,388,608 bf16
    const size_t wt_elems = 9 * 8 * 64 * 8;            // 36,864 bf16
    const size_t need = (xt_elems + wt_elems) * sizeof(ushort_t);

    if (ws_size < need) {
        dcnv2_direct<<<(BATCH * HW) / 256, 256, 0, stream>>>(x, off, msk, wgt, bias, out);
        return;
    }

    ushort_t* xt  = (ushort_t*)d_ws;
    ushort_t* wt2 = xt + xt_elems;

    dcnv2_prep<<<4096 + 18, 256, 0, stream>>>(x, wgt, xt, wt2);
    dcnv2_mfma<<<1024, 512, 0, stream>>>(xt, wt2, off, msk, bias, out);
}